// Round 5
// baseline (109.758 us; speedup 1.0000x reference)
//
#include <hip/hip_runtime.h>

// SemanticRenderer: out[r, c] = sum_{i: ray_indices[i]==r} weights[i] * semantics[i, c]
// semantics: [N, 32] f32, weights: [N] f32, ray_indices: [N] int32 (SORTED), out: [R, 32] f32
//
// Pass 0: memset seg[] (int2 per ray) to 0 -> empty rays have start==end==0.
// Pass 1 (bounds): int4-vectorized scan of ridx; run boundaries write seg[ray].
// Pass 2 (render): one wave per TWO adjacent rays (independent load chains).
//   lane = 8*g + q; per stream a load-step covers 8 rows x 128B = 1 KiB coalesced.
//   Joint loop keeps 2 streams x 2-deep = 4 KiB in flight; 4/2/1 drain ladders.
//   Fixed costs (bounds load, reduce, store, exit) amortized over ~64 samples.

typedef float f32x4 __attribute__((ext_vector_type(4)));

__global__ __launch_bounds__(256) void sr_bounds_kernel(
    const int* __restrict__ ridx, int2* __restrict__ seg, int N)
{
    const int t  = blockIdx.x * blockDim.x + threadIdx.x;
    const int i4 = t * 4;
    if (i4 >= N) return;

    if (i4 + 4 <= N) {
        const int4 v = *reinterpret_cast<const int4*>(ridx + i4);
        const int prev = (i4 == 0) ? -1 : ridx[i4 - 1];
        const int tail = (i4 + 4 < N) ? ridx[i4 + 4] : -2;   // -2 matches no ray id
        if (v.x != prev) { seg[v.x].x = i4;     if (prev >= 0) seg[prev].y = i4; }
        if (v.y != v.x)  { seg[v.y].x = i4 + 1; seg[v.x].y = i4 + 1; }
        if (v.z != v.y)  { seg[v.z].x = i4 + 2; seg[v.y].y = i4 + 2; }
        if (v.w != v.z)  { seg[v.w].x = i4 + 3; seg[v.z].y = i4 + 3; }
        if (v.w != tail) { seg[v.w].y = i4 + 4; }
    } else {
        for (int i = i4; i < N; ++i) {
            const int r    = ridx[i];
            const int prev = (i == 0) ? -1 : ridx[i - 1];
            const int next = (i == N - 1) ? -2 : ridx[i + 1];
            if (r != prev) seg[r].x = i;
            if (r != next) seg[r].y = i + 1;
        }
    }
}

__global__ __launch_bounds__(256) void SemanticRenderer_70205535421052_kernel(
    const f32x4* __restrict__ sem4,    // [N*8] (N rows of 8 float4)
    const float* __restrict__ w,       // [N]
    const int2*  __restrict__ seg,     // [R] (start, end); start==end for empty
    f32x4*       __restrict__ out4,    // [R*8]
    int R)
{
    const int wave = threadIdx.x >> 6;
    const int lane = threadIdx.x & 63;
    const int q    = lane & 7;         // class quad (classes 4q..4q+3)
    const int g    = lane >> 3;        // sample subgroup 0..7
    const int wid  = blockIdx.x * 4 + wave;
    const int r0   = wid * 2;          // this wave owns rays r0, r0+1
    if (r0 >= R) return;
    const bool two = (r0 + 1 < R);

    int sA, eA, sB, eB;
    if (two) {
        // one 16B load fetches both rays' (start,end); r0 even -> 16B aligned
        const int4 se = *reinterpret_cast<const int4*>(
            reinterpret_cast<const int*>(seg) + (size_t)r0 * 2);
        sA = se.x + g; eA = se.y;
        sB = se.z + g; eB = se.w;
    } else {
        const int2 se = seg[r0];
        sA = se.x + g; eA = se.y;
        sB = 0;        eB = 0;
    }

    f32x4 accA = (f32x4)0.f, accB = (f32x4)0.f;

    // joint loop: two independent chains, 2-deep each (4 KiB sem in flight)
    while ((sA + 8 < eA) & (sB + 8 < eB)) {
        const float wA0 = __builtin_nontemporal_load(w + sA);
        const float wA1 = __builtin_nontemporal_load(w + sA + 8);
        const float wB0 = __builtin_nontemporal_load(w + sB);
        const float wB1 = __builtin_nontemporal_load(w + sB + 8);
        const f32x4 vA0 = __builtin_nontemporal_load(sem4 + (size_t)sA * 8 + q);
        const f32x4 vA1 = __builtin_nontemporal_load(sem4 + (size_t)(sA + 8) * 8 + q);
        const f32x4 vB0 = __builtin_nontemporal_load(sem4 + (size_t)sB * 8 + q);
        const f32x4 vB1 = __builtin_nontemporal_load(sem4 + (size_t)(sB + 8) * 8 + q);
        accA += wA0 * vA0;
        accA += wA1 * vA1;
        accB += wB0 * vB0;
        accB += wB1 * vB1;
        sA += 16; sB += 16;
    }

    // per-stream drain: 4/2/1 ladder
    auto drain = [&](int s, int e, f32x4& acc) {
        for (; s + 24 < e; s += 32) {
            const float w0 = __builtin_nontemporal_load(w + s);
            const float w1 = __builtin_nontemporal_load(w + s + 8);
            const float w2 = __builtin_nontemporal_load(w + s + 16);
            const float w3 = __builtin_nontemporal_load(w + s + 24);
            const f32x4 v0 = __builtin_nontemporal_load(sem4 + (size_t)s * 8 + q);
            const f32x4 v1 = __builtin_nontemporal_load(sem4 + (size_t)(s + 8)  * 8 + q);
            const f32x4 v2 = __builtin_nontemporal_load(sem4 + (size_t)(s + 16) * 8 + q);
            const f32x4 v3 = __builtin_nontemporal_load(sem4 + (size_t)(s + 24) * 8 + q);
            acc += w0 * v0; acc += w1 * v1; acc += w2 * v2; acc += w3 * v3;
        }
        for (; s + 8 < e; s += 16) {
            const float w0 = __builtin_nontemporal_load(w + s);
            const float w1 = __builtin_nontemporal_load(w + s + 8);
            const f32x4 v0 = __builtin_nontemporal_load(sem4 + (size_t)s * 8 + q);
            const f32x4 v1 = __builtin_nontemporal_load(sem4 + (size_t)(s + 8) * 8 + q);
            acc += w0 * v0; acc += w1 * v1;
        }
        if (s < e) {
            const float w0 = __builtin_nontemporal_load(w + s);
            const f32x4 v0 = __builtin_nontemporal_load(sem4 + (size_t)s * 8 + q);
            acc += w0 * v0;
        }
    };
    drain(sA, eA, accA);
    drain(sB, eB, accB);

    // reduce both rays across the 8 sample subgroups (lane bits 3,4,5); wave=64
    #pragma unroll
    for (int m = 8; m < 64; m <<= 1) {
        accA.x += __shfl_xor(accA.x, m, 64);
        accA.y += __shfl_xor(accA.y, m, 64);
        accA.z += __shfl_xor(accA.z, m, 64);
        accA.w += __shfl_xor(accA.w, m, 64);
        accB.x += __shfl_xor(accB.x, m, 64);
        accB.y += __shfl_xor(accB.y, m, 64);
        accB.z += __shfl_xor(accB.z, m, 64);
        accB.w += __shfl_xor(accB.w, m, 64);
    }

    if (g == 0) {
        __builtin_nontemporal_store(accA, out4 + (size_t)r0 * 8 + q);
        if (two)
            __builtin_nontemporal_store(accB, out4 + (size_t)(r0 + 1) * 8 + q);
    }
}

extern "C" void kernel_launch(void* const* d_in, const int* in_sizes, int n_in,
                              void* d_out, int out_size, void* d_ws, size_t ws_size,
                              hipStream_t stream) {
    const f32x4* sem4 = (const f32x4*)d_in[0];
    const float* w    = (const float*)d_in[1];
    const int*   ridx = (const int*)d_in[2];
    f32x4*       out4 = (f32x4*)d_out;

    const int N = in_sizes[1];        // number of samples (weights is [N])
    const int R = out_size / 32;      // number of rays (out is [R,32])

    int2* seg = (int2*)d_ws;          // [R] (start, end)

    // start==end==0 for rays never written (empty) -> loop skipped -> zeros stored
    hipMemsetAsync(seg, 0, (size_t)R * sizeof(int2), stream);

    const int bthreads = (N + 3) / 4;
    sr_bounds_kernel<<<(bthreads + 255) / 256, 256, 0, stream>>>(ridx, seg, N);

    const int blocks = (R + 7) / 8;   // 8 rays (4 waves x 2 rays) per block
    SemanticRenderer_70205535421052_kernel<<<blocks, 256, 0, stream>>>(
        sem4, w, seg, out4, R);
}